// Round 8
// baseline (61344.830 us; speedup 1.0000x reference)
//
#include <hip/hip_runtime.h>
#include <math.h>

#define TT 8192
#define HH 512
#define LL 5
#define OO 256
#define GG 32           // workgroups per layer (16 rows each; 4 rows per wave)
#define NTHR 256
#define RB 64           // h ring depth (power of 2)
#define CAP_TAG 4000000u
#define CAP_PRG 4000000u

typedef unsigned long long u64;
typedef unsigned u32;

// ---------------- helpers ----------------

__device__ __forceinline__ float wred(float v) {
#pragma unroll
  for (int off = 32; off > 0; off >>= 1) v += __shfl_xor(v, off, 64);
  return v;
}

__device__ __forceinline__ float sigm(float v) {
  return 1.0f / (1.0f + expf(-v));
}

__device__ __forceinline__ u64 ldA(const u64* p) {
  return __hip_atomic_load((u64*)p, __ATOMIC_RELAXED, __HIP_MEMORY_SCOPE_AGENT);
}
__device__ __forceinline__ void stA(u64* p, u64 v) {
  __hip_atomic_store(p, v, __ATOMIC_RELAXED, __HIP_MEMORY_SCOPE_AGENT);
}
__device__ __forceinline__ u32 ld32(const u32* p) {
  return __hip_atomic_load((u32*)p, __ATOMIC_RELAXED, __HIP_MEMORY_SCOPE_AGENT);
}
__device__ __forceinline__ void st32(u32* p, u32 v) {
  __hip_atomic_store(p, v, __ATOMIC_RELAXED, __HIP_MEMORY_SCOPE_AGENT);
}
__device__ __forceinline__ u64 pack(u32 tag, float v) {
  return ((u64)tag << 32) | (u64)__float_as_uint(v);
}

// ---------------- init: zero rings + prog each call ----------------

__global__ void init_ws(u32* __restrict__ p, int n) {
  int stride = gridDim.x * blockDim.x;
  for (int i = blockIdx.x * blockDim.x + threadIdx.x; i < n; i += stride) p[i] = 0u;
}

// ---------------- persistent GRU pipeline (wave-autonomous) ----------------
// LL*GG = 160 blocks x 256 threads (1 block/CU). Each WAVE is an independent
// agent owning 4 contiguous rows; no __syncthreads in the hot loop, no LDS.
// Column mapping is TRANSPOSED: lane L covers columns {L + 64q} of every dot
// product (wred makes the mapping irrelevant), so every tagged-slot poll
// instruction reads 64 consecutive u64s -> fully coalesced. Exchange protocol:
// tagged 64-bit relaxed agent atomics (tag = t+1), self-validating, no fences.
// The r exchange carries rh = r * h_prev directly (producer owns h_prev in a
// lane-0 register), removing the consumer-side rh build entirely.

__launch_bounds__(NTHR, 1)
__global__ void gru_pipeline(
    const float* __restrict__ x,
    const float* __restrict__ Wz, const float* __restrict__ bWz,
    const float* __restrict__ Uz, const float* __restrict__ bUz,
    const float* __restrict__ Wr, const float* __restrict__ bWr,
    const float* __restrict__ Ur, const float* __restrict__ bUr,
    const float* __restrict__ Wh, const float* __restrict__ bWh,
    const float* __restrict__ Uh, const float* __restrict__ bUh,
    u64* __restrict__ hring,           // [LL][RB][HH] tagged
    u64* __restrict__ rring,           // [LL][2][HH] tagged (holds rh)
    float* __restrict__ htop,          // [TT][HH] plain (FC input)
    u32* __restrict__ prog,            // [LL][GG][4] per-wave staging progress
    float* __restrict__ dout)
{
  const int blk = blockIdx.x;
  const int l = blk / GG;
  const int g = blk % GG;
  const bool ltop = (l == LL - 1);
  const int tid = threadIdx.x;
  const int wave = tid >> 6;
  const int lane = tid & 63;
  const int i0 = g * 16 + wave * 4;    // this wave's 4 contiguous rows

  __shared__ int dead_s;               // watchdog latch (anti-hang)
  volatile int* dead = &dead_s;
  if (tid == 0) dead_s = 0;

  // VGPR-resident weights, transposed col mapping c(q) = lane + 64q
  float wz[4][8], uz[4][8], wr[4][8], ur[4][8], wh[4][8], uh[4][8];
  float bz[4], br[4], bh[4];
#pragma unroll
  for (int k = 0; k < 4; ++k) {
    const int i = i0 + k;
    const size_t ro = ((size_t)l * HH + i) * HH + lane;
#pragma unroll
    for (int q = 0; q < 8; ++q) {
      wz[k][q] = Wz[ro + 64 * q];
      uz[k][q] = Uz[ro + 64 * q];
      wr[k][q] = Wr[ro + 64 * q];
      ur[k][q] = Ur[ro + 64 * q];
      wh[k][q] = Wh[ro + 64 * q];
      uh[k][q] = Uh[ro + 64 * q];
    }
    bz[k] = bWz[l * HH + i] + bUz[l * HH + i];
    br[k] = bWr[l * HH + i] + bUr[l * HH + i];
    bh[k] = bWh[l * HH + i] + bUh[l * HH + i];
  }

  u64* my_h = hring + (size_t)l * RB * HH;
  const u64* up_h = hring + (size_t)(l > 0 ? l - 1 : 0) * RB * HH;
  u64* my_r = rring + (size_t)l * 2 * HH;
  u32* my_prog = prog + ((size_t)l * GG + g) * 4 + wave;
  const u32* dnp = prog + (size_t)(l < LL - 1 ? l + 1 : l) * GG * 4;

  float hprev[4] = {0.f, 0.f, 0.f, 0.f};   // own rows' h (lane-0 meaningful)

  __syncthreads();   // dead_s visible; only barrier in the kernel

  for (int t = 0; t < TT; ++t) {
    // ---- A: back-pressure (rare): down layer consumed slot we'll overwrite
    if (!ltop && t >= RB) {
      const u32 need = (u32)(t - RB + 1);
      u32 n = 0;
      while (ld32(dnp + lane) < need || ld32(dnp + 64 + lane) < need) {
        __builtin_amdgcn_s_sleep(16);
        if (*dead) break;
        if (++n > CAP_PRG) { *dead = 1; break; }
      }
    }

    // ---- B: stage xv, hv (joint tagged poll, coalesced, sleep-paced) ----
    float xv[8], hv[8];
    {
      const u64* sx = (l > 0) ? up_h + (size_t)(t & (RB - 1)) * HH : (const u64*)0;
      const u64* sh = (t > 0) ? my_h + (size_t)((t - 1) & (RB - 1)) * HH : (const u64*)0;
      const u32 tgx = (u32)(t + 1), tgh = (u32)t;
      u64 vx[8], vh[8];
      u32 mx = sx ? 0xFFu : 0u, mh = sh ? 0xFFu : 0u, n = 0;
      while (mx | mh) {
#pragma unroll
        for (int q = 0; q < 8; ++q) if (mx & (1u << q)) vx[q] = ldA(sx + lane + 64 * q);
#pragma unroll
        for (int q = 0; q < 8; ++q) if (mh & (1u << q)) vh[q] = ldA(sh + lane + 64 * q);
#pragma unroll
        for (int q = 0; q < 8; ++q)
          if ((mx & (1u << q)) && (u32)(vx[q] >> 32) == tgx) mx &= ~(1u << q);
#pragma unroll
        for (int q = 0; q < 8; ++q)
          if ((mh & (1u << q)) && (u32)(vh[q] >> 32) == tgh) mh &= ~(1u << q);
        if (!(mx | mh)) break;
        __builtin_amdgcn_s_sleep(2);
        if (*dead) break;
        if (++n > CAP_TAG) { *dead = 1; break; }
      }
      if (sx) {
#pragma unroll
        for (int q = 0; q < 8; ++q) xv[q] = __uint_as_float((u32)vx[q]);
      } else {
#pragma unroll
        for (int q = 0; q < 8; ++q) xv[q] = x[(size_t)t * HH + lane + 64 * q];
      }
      if (sh) {
#pragma unroll
        for (int q = 0; q < 8; ++q) hv[q] = __uint_as_float((u32)vh[q]);
      } else {
#pragma unroll
        for (int q = 0; q < 8; ++q) hv[q] = 0.f;
      }
    }

    // ---- C: publish this wave's staging progress (enables up-layer reuse)
    if (lane == 0) st32(my_prog, (u32)(t + 1));

    u64* hsl = my_h + (size_t)(t & (RB - 1)) * HH;

    if (t == 0) {
      // h_prev = 0: h = z * tanh(Wh x + bh)
#pragma unroll
      for (int k = 0; k < 4; ++k) {
        float az = 0.f, aw = 0.f;
#pragma unroll
        for (int q = 0; q < 8; ++q) {
          az = fmaf(wz[k][q], xv[q], az);
          aw = fmaf(wh[k][q], xv[q], aw);
        }
        az = wred(az); aw = wred(aw);
        if (lane == 0) {
          const float hnew = sigm(az + bz[k]) * tanhf(aw + bh[k]);
          hprev[k] = hnew;
          stA(&hsl[i0 + k], pack(1u, hnew));
          if (ltop) htop[i0 + k] = hnew;
        }
      }
      continue;
    }

    const u32 tg = (u32)(t + 1);
    u64* rs = my_r + (size_t)(t & 1) * HH;

    // ---- D: r per owned row; publish rh = r * h_prev immediately ----
#pragma unroll
    for (int k = 0; k < 4; ++k) {
      float ar = 0.f;
#pragma unroll
      for (int q = 0; q < 8; ++q) {
        ar = fmaf(wr[k][q], xv[q], ar);
        ar = fmaf(ur[k][q], hv[q], ar);
      }
      ar = wred(ar);
      if (lane == 0) stA(&rs[i0 + k], pack(tg, sigm(ar + br[k]) * hprev[k]));
    }

    // ---- E: z and Wh·x (overlaps the rh round trip) ----
    float zk[4], awk[4];
#pragma unroll
    for (int k = 0; k < 4; ++k) {
      float az = 0.f, aw = 0.f;
#pragma unroll
      for (int q = 0; q < 8; ++q) {
        az = fmaf(wz[k][q], xv[q], az);
        az = fmaf(uz[k][q], hv[q], az);
        aw = fmaf(wh[k][q], xv[q], aw);
      }
      az = wred(az); aw = wred(aw);
      zk[k] = sigm(az + bz[k]);
      awk[k] = aw + bh[k];
    }

    // ---- F: poll rh (tagged, coalesced, sleep-paced) ----
    float rhv[8];
    {
      const u64* s = rs;
      u64 v[8];
      u32 m = 0xFFu, n = 0;
      for (;;) {
#pragma unroll
        for (int q = 0; q < 8; ++q) if (m & (1u << q)) v[q] = ldA(s + lane + 64 * q);
#pragma unroll
        for (int q = 0; q < 8; ++q)
          if ((m & (1u << q)) && (u32)(v[q] >> 32) == tg) m &= ~(1u << q);
        if (!m) break;
        __builtin_amdgcn_s_sleep(2);
        if (*dead) break;
        if (++n > CAP_TAG) { *dead = 1; break; }
      }
#pragma unroll
      for (int q = 0; q < 8; ++q) rhv[q] = __uint_as_float((u32)v[q]);
    }

    // ---- G: Uh·rh, gate combine, publish h ----
#pragma unroll
    for (int k = 0; k < 4; ++k) {
      float u = 0.f;
#pragma unroll
      for (int q = 0; q < 8; ++q) u = fmaf(uh[k][q], rhv[q], u);
      u = wred(u);
      if (lane == 0) {
        const float ht = tanhf(awk[k] + u);
        const float hnew = (1.f - zk[k]) * hprev[k] + zk[k] * ht;
        hprev[k] = hnew;
        stA(&hsl[i0 + k], pack(tg, hnew));
        if (ltop) htop[(size_t)t * HH + i0 + k] = hnew;
        if (t == TT - 1) dout[(size_t)TT * OO + (size_t)l * HH + i0 + k] = hnew;
      }
    }
  }
}

// ---------------- final FC: out[T,O] = outs[T,H] @ fcW[O,H]^T + fcb ----------------

__launch_bounds__(256)
__global__ void fc_gemm(const float* __restrict__ A,   // [TT][HH] (top-layer h)
                        const float* __restrict__ W,   // [OO][HH]
                        const float* __restrict__ bias, // [OO]
                        float* __restrict__ C) {       // [TT][OO]
  __shared__ float As[16][68];
  __shared__ float Ws[16][68];
  const int bm = blockIdx.x;        // TT/64
  const int bn = blockIdx.y;        // OO/64
  const int tid = threadIdx.x;
  const int tx = tid & 15;
  const int ty = tid >> 4;
  const int r = tid >> 2;           // 0..63
  const int kc = (tid & 3) * 4;     // 0,4,8,12
  float acc[4][4];
#pragma unroll
  for (int a = 0; a < 4; ++a)
#pragma unroll
    for (int b2 = 0; b2 < 4; ++b2) acc[a][b2] = 0.f;

  for (int k0 = 0; k0 < HH; k0 += 16) {
    const float4 a4 = *(const float4*)&A[(size_t)(bm * 64 + r) * HH + k0 + kc];
    const float4 w4 = *(const float4*)&W[(size_t)(bn * 64 + r) * HH + k0 + kc];
    __syncthreads();
    As[kc + 0][r] = a4.x; As[kc + 1][r] = a4.y; As[kc + 2][r] = a4.z; As[kc + 3][r] = a4.w;
    Ws[kc + 0][r] = w4.x; Ws[kc + 1][r] = w4.y; Ws[kc + 2][r] = w4.z; Ws[kc + 3][r] = w4.w;
    __syncthreads();
#pragma unroll
    for (int kk = 0; kk < 16; ++kk) {
      const float4 av = *(const float4*)&As[kk][ty * 4];
      const float4 wv = *(const float4*)&Ws[kk][tx * 4];
      const float avv[4] = {av.x, av.y, av.z, av.w};
      const float wvv[4] = {wv.x, wv.y, wv.z, wv.w};
#pragma unroll
      for (int a = 0; a < 4; ++a)
#pragma unroll
        for (int b2 = 0; b2 < 4; ++b2)
          acc[a][b2] = fmaf(avv[a], wvv[b2], acc[a][b2]);
    }
  }
#pragma unroll
  for (int a = 0; a < 4; ++a) {
    const int row = bm * 64 + ty * 4 + a;
#pragma unroll
    for (int b2 = 0; b2 < 4; ++b2) {
      const int col = bn * 64 + tx * 4 + b2;
      C[(size_t)row * OO + col] = acc[a][b2] + bias[col];
    }
  }
}

// ---------------- launch ----------------

extern "C" void kernel_launch(void* const* d_in, const int* in_sizes, int n_in,
                              void* d_out, int out_size, void* d_ws, size_t ws_size,
                              hipStream_t stream) {
  const float* p[15];
  for (int i = 0; i < 15 && i < n_in; ++i) p[i] = (const float*)d_in[i];

  const float *x, *Wz, *bWz, *Uz, *bUz, *Wr, *bWr, *Ur, *bUr, *Wh, *bWh, *Uh, *bUh, *fcW, *fcb;
  x = p[0];
  if (in_sizes[2] == LL * HH) {
    // setup_inputs() dict order: x, Wz, bWz, Uz, bUz, Wr, bWr, Ur, bUr, Wh, bWh, Uh, bUh, fcW, fcb
    Wz = p[1]; bWz = p[2]; Uz = p[3]; bUz = p[4];
    Wr = p[5]; bWr = p[6]; Ur = p[7]; bUr = p[8];
    Wh = p[9]; bWh = p[10]; Uh = p[11]; bUh = p[12];
  } else {
    // signature order fallback
    Wz = p[1]; Uz = p[2]; Wr = p[3]; Ur = p[4]; Wh = p[5]; Uh = p[6];
    bWz = p[7]; bUz = p[8]; bWr = p[9]; bUr = p[10]; bWh = p[11]; bUh = p[12];
  }
  fcW = p[13]; fcb = p[14];

  // workspace: [hring u64 LL*RB*HH | rring u64 LL*2*HH | prog u32 LL*GG*4 | htop f32 TT*HH]
  u64* hring = (u64*)d_ws;
  u64* rring = hring + (size_t)LL * RB * HH;
  u32* prog = (u32*)(rring + (size_t)LL * 2 * HH);
  float* htop = (float*)(prog + (size_t)LL * GG * 4);

  const int zero_u32 = (int)(((size_t)LL * RB * HH + (size_t)LL * 2 * HH) * 2
                             + (size_t)LL * GG * 4);
  init_ws<<<512, 256, 0, stream>>>((u32*)d_ws, zero_u32);

  gru_pipeline<<<LL * GG, NTHR, 0, stream>>>(
      x, Wz, bWz, Uz, bUz, Wr, bWr, Ur, bUr, Wh, bWh, Uh, bUh,
      hring, rring, htop, prog, (float*)d_out);

  fc_gemm<<<dim3(TT / 64, OO / 64), 256, 0, stream>>>(
      htop, fcW, fcb, (float*)d_out);
}